// Round 18
// baseline (174.167 us; speedup 1.0000x reference)
//
#include <hip/hip_runtime.h>
#include <hip/hip_bf16.h>
#include <math.h>

#define B_    4
#define C_    192
#define NPT   3136          // H*W points per batch
#define CO_   384           // Cout
#define KNN   9
#define K2    16            // exact-refine set size (approx-top-16 of 63)
#define NROWS (B_*NPT)      // 12544 total points
#define SD    10            // per-list screening depth
#define NSCRB (7*196)       // screen blocks
#define NREFB (NROWS/4)     // refine blocks (3136)

typedef _Float16 half8 __attribute__((ext_vector_type(8)));
typedef float    f32x4 __attribute__((ext_vector_type(4)));

__device__ __forceinline__ float u2f(unsigned short u) {
    unsigned int t = ((unsigned int)u) << 16;
    float f; __builtin_memcpy(&f, &t, 4); return f;
}
__device__ __forceinline__ unsigned short f2u(float f) {
    __hip_bfloat16 h = __float2bfloat16(f);
    unsigned short u; __builtin_memcpy(&u, &h, 2); return u;
}
__device__ __forceinline__ float gelu_exact(float y) {
    return 0.5f * y * (1.0f + erff(y * 0.70710678118654752f));
}
// sortable u64 key for an f64 (ascending double order == ascending u64 order)
__device__ __forceinline__ unsigned long long dkey(double d) {
    long long sb = __double_as_longlong(d);
    unsigned long long u = (unsigned long long)sb;
    return (sb < 0) ? ~u : (u | 0x8000000000000000ULL);
}

// ---------------------------------------------------------------------------
// K1 v5: per-point f64 norm stats (+ fp32 norm) with co-dispatched weight
//   pack (blocks >= 196; disjoint outputs).
// ---------------------------------------------------------------------------
__global__ __launch_bounds__(256) void k_norm(
    const float* __restrict__ x,
    float* __restrict__ invn32, double* __restrict__ invn64,
    double* __restrict__ sqd, float* __restrict__ nrm32,
    const float* __restrict__ cw, _Float16* __restrict__ wpk)
{
    __shared__ double part[4][64];
    if (blockIdx.x >= 196) {            // weight-pack blocks (72)
        int t = (blockIdx.x - 196) * 256 + threadIdx.x;  // 0..18431
        int l  = t & 63;
        int tk = t >> 6;                // ot*6+kk
        int kk = tk % 6, ot = tk / 6;
        int hsel = ot / 24;
        int o = (ot % 24) * 16 + (l & 15);
        int k = kk * 32 + (l >> 4) * 8;
        half8 h;
#pragma unroll
        for (int e = 0; e < 8; ++e) {
            float w2 = cw[(size_t)o * 384 + C_ + k + e];
            float wv = hsel ? w2 : (cw[(size_t)o * 384 + k + e] - w2);
            h[e] = (_Float16)wv;
        }
        *(half8*)(wpk + (size_t)t * 8) = h;
        return;
    }
    int wave = threadIdx.x >> 6, lane = threadIdx.x & 63;
    int p0 = blockIdx.x * 64;          // 64 points per block, 196 blocks
    int row = p0 + lane;
    int b = row / NPT, n = row % NPT;
    const float* xb = x + (size_t)b * C_ * NPT + n;
    double S = 0.0;
    int c0 = wave * 48;
    for (int c = c0; c < c0 + 48; ++c) {
        double v = (double)xb[(size_t)c * NPT];
        S = fma(v, v, S);
    }
    part[wave][lane] = S;
    __syncthreads();
    if (threadIdx.x < 64) {
        double T = ((part[0][lane] + part[1][lane]) + part[2][lane])
                 + part[3][lane];
        double nrm = sqrt(T);
        if (nrm < 1e-12) nrm = 1e-12;
        double iv = 1.0 / nrm;
        int prow = p0 + lane;
        invn64[prow] = iv;
        invn32[prow] = (float)iv;
        sqd[prow] = iv * iv * T;
        nrm32[prow] = (float)nrm;
    }
}

// ---------------------------------------------------------------------------
// K1b v2: LDS-tiled transpose x -> xT (fp32, exact) + fused fp16 pack.
// ---------------------------------------------------------------------------
__global__ __launch_bounds__(256) void k_xpose(
    const float* __restrict__ x, float* __restrict__ xT,
    const float* __restrict__ invn32, _Float16* __restrict__ packed)
{
    __shared__ float t[32][33];
    int blk = blockIdx.x;
    int b  = blk / 588;
    int r  = blk % 588;
    int ct = r / 98, nt = r % 98;
    int c0 = ct * 32, n0 = nt * 32;
    int tid = threadIdx.x;
    int tx = tid & 31, ty8 = tid >> 5;          // 8 rows per pass
    const float* xb = x + (size_t)b * C_ * NPT;
#pragma unroll
    for (int e = 0; e < 4; ++e) {
        int cc = ty8 + e * 8;
        t[cc][tx] = xb[(size_t)(c0 + cc) * NPT + n0 + tx];
    }
    __syncthreads();
#pragma unroll
    for (int e = 0; e < 4; ++e) {
        int nn = ty8 + e * 8;
        xT[(size_t)(b * NPT + n0 + nn) * C_ + c0 + tx] = t[tx][nn];
    }
    if (tid < 128) {
        int f = tid >> 6, l = tid & 63;
        int pt = f * 16 + (l & 15);            // tile-local point
        float iv = invn32[(size_t)b * NPT + n0 + pt];
        int cb = (l >> 4) * 8;                 // tile-local channel base
        half8 h;
#pragma unroll
        for (int e = 0; e < 8; ++e)
            h[e] = (_Float16)(t[cb + e][pt] * iv);
        size_t idx = ((((size_t)(b * 196 + nt * 2 + f)) * 6 + ct) * 64 + l) * 8;
        *(half8*)(packed + idx) = h;
    }
}

// ---------------------------------------------------------------------------
// K2: MFMA screening (proven R17 body: transposed md[80][64], 20,480 B).
// ---------------------------------------------------------------------------
__global__ __launch_bounds__(256) void k_screen_mfma(
    const _Float16* __restrict__ packed, unsigned* __restrict__ cand)
{
    __shared__ unsigned md[8 * SD][64];   // 20,480 B
    int blk   = blockIdx.x;
    int chunk = blk / 196;               // 0..6
    int t2    = blk % 196;
    int b     = t2 / 49;
    int itile = t2 % 49;                 // 64-row i tile
    int tid   = threadIdx.x;
    int wave  = tid >> 6, lane = tid & 63;
    int it    = itile * 4 + wave;        // global 16-row tile within batch

    const _Float16* pb = packed + ((size_t)(b * 196 + it) * 6) * 512 + lane * 8;
    half8 bf[6];
#pragma unroll
    for (int kk = 0; kk < 6; ++kk)
        bf[kk] = *(const half8*)(pb + kk * 512);

    int jt0 = chunk * 28;                 // 7 chunks x 28 tiles (uniform)
    const int ntj = 28;

    unsigned bdA[SD], bdB[SD];
#pragma unroll
    for (int q = 0; q < SD; ++q) { bdA[q] = 0u; bdB[q] = 0u; }

    const _Float16* pa_base =
        packed + ((size_t)(b * 196 + jt0) * 6) * 512 + lane * 8;

    half8 af[6];
#pragma unroll
    for (int kk = 0; kk < 6; ++kk)
        af[kk] = *(const half8*)(pa_base + kk * 512);

    for (int jt = 0; jt < ntj; ++jt) {
        f32x4 acc = {0.f, 0.f, 0.f, 0.f};
#pragma unroll
        for (int kk = 0; kk < 6; ++kk)
            acc = __builtin_amdgcn_mfma_f32_16x16x32_f16(af[kk], bf[kk], acc, 0, 0, 0);

        if (jt + 1 < ntj) {
            const _Float16* pn = pa_base + (size_t)(jt + 1) * 6 * 512;
#pragma unroll
            for (int kk = 0; kk < 6; ++kk)
                af[kk] = *(const half8*)(pn + kk * 512);
        }

        unsigned jb = (unsigned)((jt0 + jt) * 16 + (lane >> 4) * 4);
        // list A: acc[0], acc[1]   (independent chain from list B)
#pragma unroll
        for (int q = 0; q < 2; ++q) {
            unsigned fb = __float_as_uint(acc[q] + 2.0f);
            unsigned c = (fb & 0xFFFFF000u) | (jb + (unsigned)q);
#pragma unroll
            for (int t = 0; t < SD; ++t) {
                unsigned old = bdA[t];
                unsigned mx = old > c ? old : c;
                c           = old > c ? c : old;
                bdA[t] = mx;
            }
        }
        // list B: acc[2], acc[3]
#pragma unroll
        for (int q = 2; q < 4; ++q) {
            unsigned fb = __float_as_uint(acc[q] + 2.0f);
            unsigned c = (fb & 0xFFFFF000u) | (jb + (unsigned)q);
#pragma unroll
            for (int t = 0; t < SD; ++t) {
                unsigned old = bdB[t];
                unsigned mx = old > c ? old : c;
                c           = old > c ? c : old;
                bdB[t] = mx;
            }
        }
    }

    int ir = wave * 16 + (lane & 15);    // i-row within block (0..63)
    int g  = lane >> 4;                  // lane group -> streams 2g, 2g+1
#pragma unroll
    for (int q = 0; q < SD; ++q) {
        md[(g * 2 + 0) * SD + q][ir] = bdA[q];
        md[(g * 2 + 1) * SD + q][ir] = bdB[q];
    }
    __syncthreads();

    if (tid < 64) {
        int h[8] = {0, 0, 0, 0, 0, 0, 0, 0};
        size_t rowi = (size_t)b * NPT + itile * 64 + tid;
        unsigned* cp = cand + rowi * 64 + chunk * 9;
        const unsigned* rd = &md[0][tid];
        for (int s = 0; s < 9; ++s) {
            unsigned best = 0u; int bg = 0;
#pragma unroll
            for (int g2 = 0; g2 < 8; ++g2) {
                unsigned v = (h[g2] < SD) ? rd[(g2 * SD + h[g2]) * 64] : 0u;
                if (v > best) { best = v; bg = g2; }
            }
            cp[s] = best;
            h[bg]++;
        }
        if (chunk == 0)                   // sentinel slot 63: key 0
            cand[rowi * 64 + 63] = 0u;
    }
}

// ---------------------------------------------------------------------------
// dev_refine: key-merge + exact f64 refine body (proven R17 code, verbatim;
//   shared arrays declared inside — legal, per-block static).
// ---------------------------------------------------------------------------
__device__ __forceinline__ void dev_refine(
    const float* __restrict__ xT, const double* __restrict__ invn64,
    const double* __restrict__ sqd, const unsigned* __restrict__ cand32,
    float* __restrict__ e0, int blk)
{
    __shared__ unsigned km[4][64];
    __shared__ int    icand[4][K2];
    __shared__ double civ[4][K2];
    __shared__ double csq[4][K2];
    __shared__ unsigned long long kbuf[4][K2];
    __shared__ float  xi[4][C_];
    int wave = threadIdx.x >> 6;
    int lane = threadIdx.x & 63;
    int row  = blk * 4 + wave;
    int b    = row / NPT;
    size_t bN = (size_t)b * NPT;

    unsigned kc = cand32[(size_t)row * 64 + lane];
    km[wave][lane] = kc;
    const float* xiRow = xT + (size_t)row * C_;
    xi[wave][lane]       = xiRow[lane];
    xi[wave][lane + 64]  = xiRow[lane + 64];
    xi[wave][lane + 128] = xiRow[lane + 128];
    __syncthreads();

    // approx rank (descending key); keys distinct -> permutation 0..63
    int keyrank = 0;
#pragma unroll
    for (int m = 0; m < 64; ++m)
        keyrank += (km[wave][m] > kc) ? 1 : 0;
    if (keyrank < K2)
        icand[wave][keyrank] = (int)(kc & 0xFFFu);
    __syncthreads();
    if (lane < K2) {
        int j = icand[wave][lane];
        civ[wave][lane] = invn64[bN + j];
        csq[wave][lane] = sqd[bN + j];
    }
    __syncthreads();

    int sub = lane & 7, cg = lane >> 3;
    double ivi = invn64[row], sqi = sqd[row];
    const float* xw = &xi[wave][sub * 4];

    // prologue: first half of candidate cg
    float4 h0a, h0b, h0c;
    {
        int j0 = icand[wave][cg];
        const float* p = xT + (bN + j0) * C_ + sub * 4;
        h0a = *(const float4*)&p[0];
        h0b = *(const float4*)&p[32];
        h0c = *(const float4*)&p[64];
    }

#pragma unroll
    for (int cc = 0; cc < K2 / 8; ++cc) {
        int cidx = cc * 8 + cg;
        int jcur = icand[wave][cidx];
        const float* pc = xT + (bN + jcur) * C_ + sub * 4;
        float4 h1a = *(const float4*)&pc[96];
        float4 h1b = *(const float4*)&pc[128];
        float4 h1c = *(const float4*)&pc[160];

        double d0 = 0.0, d1 = 0.0, d2 = 0.0, d3 = 0.0;
        {
            float4 xq;
            xq = *(const float4*)&xw[0];
            d0 = fma((double)xq.x, (double)h0a.x, d0);
            d1 = fma((double)xq.y, (double)h0a.y, d1);
            d2 = fma((double)xq.z, (double)h0a.z, d2);
            d3 = fma((double)xq.w, (double)h0a.w, d3);
            xq = *(const float4*)&xw[32];
            d0 = fma((double)xq.x, (double)h0b.x, d0);
            d1 = fma((double)xq.y, (double)h0b.y, d1);
            d2 = fma((double)xq.z, (double)h0b.z, d2);
            d3 = fma((double)xq.w, (double)h0b.w, d3);
            xq = *(const float4*)&xw[64];
            d0 = fma((double)xq.x, (double)h0c.x, d0);
            d1 = fma((double)xq.y, (double)h0c.y, d1);
            d2 = fma((double)xq.z, (double)h0c.z, d2);
            d3 = fma((double)xq.w, (double)h0c.w, d3);
        }
        if (cc < K2 / 8 - 1) {
            int jn = icand[wave][cidx + 8];
            const float* pn = xT + (bN + jn) * C_ + sub * 4;
            h0a = *(const float4*)&pn[0];
            h0b = *(const float4*)&pn[32];
            h0c = *(const float4*)&pn[64];
        }
        {
            float4 xq;
            xq = *(const float4*)&xw[96];
            d0 = fma((double)xq.x, (double)h1a.x, d0);
            d1 = fma((double)xq.y, (double)h1a.y, d1);
            d2 = fma((double)xq.z, (double)h1a.z, d2);
            d3 = fma((double)xq.w, (double)h1a.w, d3);
            xq = *(const float4*)&xw[128];
            d0 = fma((double)xq.x, (double)h1b.x, d0);
            d1 = fma((double)xq.y, (double)h1b.y, d1);
            d2 = fma((double)xq.z, (double)h1b.z, d2);
            d3 = fma((double)xq.w, (double)h1b.w, d3);
            xq = *(const float4*)&xw[160];
            d0 = fma((double)xq.x, (double)h1c.x, d0);
            d1 = fma((double)xq.y, (double)h1c.y, d1);
            d2 = fma((double)xq.z, (double)h1c.z, d2);
            d3 = fma((double)xq.w, (double)h1c.w, d3);
        }
        double dot = (d0 + d1) + (d2 + d3);
        dot += __shfl_xor(dot, 1);
        dot += __shfl_xor(dot, 2);
        dot += __shfl_xor(dot, 4);
        if (sub == 0) {
            double dist = sqi + csq[wave][cidx]
                        - 2.0 * (ivi * civ[wave][cidx] * dot);
            kbuf[wave][cidx] = dkey(dist);
        }
    }
    __syncthreads();

    // exact rank-based top-9 over the K2 refined candidates
    if (lane < K2) {
        unsigned long long kd = kbuf[wave][lane];
        int jme = icand[wave][lane];
        int rank = 0;
#pragma unroll
        for (int m = 0; m < K2; ++m) {
            unsigned long long km2 = kbuf[wave][m];
            int jm = icand[wave][m];
            rank += ((km2 < kd) || (km2 == kd && jm < jme)) ? 1 : 0;
        }
        if (rank < KNN)
            e0[(size_t)row * KNN + rank] = (float)jme;
    }
}

// ---------------------------------------------------------------------------
// dev_gemm: MFMA dual-GEMM body (proven R12/R14/R15 code, verbatim).
// ---------------------------------------------------------------------------
__device__ __forceinline__ void dev_gemm(
    const _Float16* __restrict__ packed, const _Float16* __restrict__ wpk,
    const float* __restrict__ nrm32, const float* __restrict__ cb,
    unsigned short* __restrict__ Bh, float* __restrict__ Zf, int pt)
{
    int wave = threadIdx.x >> 6, lane = threadIdx.x & 63;
    int hsel = wave >> 1;               // 0: Zf, 1: Bh
    int og   = wave & 1;                // o half within 384

    const _Float16* px = packed + (size_t)pt * 6 * 512 + lane * 8;
    half8 pf[6];
#pragma unroll
    for (int kk = 0; kk < 6; ++kk) pf[kk] = *(const half8*)(px + kk * 512);

    float s = nrm32[pt * 16 + (lane & 15)];
    size_t row0 = (size_t)pt * 16 + (lane & 15);
    int olane = (lane >> 4) * 4;

    int ot0 = hsel * 24 + og * 12;
    const _Float16* wb = wpk + (size_t)ot0 * 6 * 512 + lane * 8;

    half8 wf[6];
#pragma unroll
    for (int kk = 0; kk < 6; ++kk) wf[kk] = *(const half8*)(wb + kk * 512);

    for (int t = 0; t < 12; ++t) {
        f32x4 acc = {0.f, 0.f, 0.f, 0.f};
#pragma unroll
        for (int kk = 0; kk < 6; ++kk)
            acc = __builtin_amdgcn_mfma_f32_16x16x32_f16(wf[kk], pf[kk], acc, 0, 0, 0);

        if (t < 11) {
            const _Float16* wn = wb + (size_t)(t + 1) * 6 * 512;
#pragma unroll
            for (int kk = 0; kk < 6; ++kk)
                wf[kk] = *(const half8*)(wn + kk * 512);
        }

        int o = (og * 12 + t) * 16 + olane;
        if (hsel == 0) {
            float4 cbv = *(const float4*)&cb[o];
            float4 zv;
            zv.x = acc[0] * s + cbv.x; zv.y = acc[1] * s + cbv.y;
            zv.z = acc[2] * s + cbv.z; zv.w = acc[3] * s + cbv.w;
            *(float4*)&Zf[row0 * 384 + o] = zv;
        } else {
            ushort4 pk;
            pk.x = f2u(acc[0] * s); pk.y = f2u(acc[1] * s);
            pk.z = f2u(acc[2] * s); pk.w = f2u(acc[3] * s);
            *(ushort4*)&Bh[row0 * 384 + o] = pk;
        }
    }
}

// ---------------------------------------------------------------------------
// K3: standalone refine (medium/fallback paths).
// ---------------------------------------------------------------------------
__global__ __launch_bounds__(256) void k_refine(
    const float* __restrict__ xT, const double* __restrict__ invn64,
    const double* __restrict__ sqd, const unsigned* __restrict__ cand32,
    float* __restrict__ e0)
{
    dev_refine(xT, invn64, sqd, cand32, e0, blockIdx.x);
}

// ---------------------------------------------------------------------------
// K3g: FUSED refine + gemm co-dispatch (fast path). Blocks [0,NREFB) run
//   refine (critical path, dispatched first); [NREFB,NREFB+784) run the
//   dual GEMM, back-filling. Complementary pipes: refine = f64 FMA +
//   scattered fp32 L2 loads; gemm = fp16 MFMA + streaming stores.
//   Disjoint operands: refine r{cand32,xT,stats} w{e0}; gemm
//   r{packed,wpk,nrm32,cb} w{Bh,Zf in d_ws}. out2 (reader of Bh/Zf/e0)
//   launches after. Branch is block-uniform.
// ---------------------------------------------------------------------------
__global__ __launch_bounds__(256) void k_refine_gemm(
    const float* __restrict__ xT, const double* __restrict__ invn64,
    const double* __restrict__ sqd, const unsigned* __restrict__ cand32,
    float* __restrict__ e0,
    const _Float16* __restrict__ packed, const _Float16* __restrict__ wpk,
    const float* __restrict__ nrm32, const float* __restrict__ cb,
    unsigned short* __restrict__ Bh, float* __restrict__ Zf)
{
    if (blockIdx.x < NREFB)
        dev_refine(xT, invn64, sqd, cand32, e0, blockIdx.x);
    else
        dev_gemm(packed, wpk, nrm32, cb, Bh, Zf, blockIdx.x - NREFB);
}

// ---------------------------------------------------------------------------
// K4c: standalone gemm (medium-path unused; kept for symmetry/testing).
// ---------------------------------------------------------------------------
__global__ __launch_bounds__(256) void k_gemm_mfma(
    const _Float16* __restrict__ packed, const _Float16* __restrict__ wpk,
    const float* __restrict__ nrm32, const float* __restrict__ cb,
    unsigned short* __restrict__ Bh, float* __restrict__ Zf)
{
    dev_gemm(packed, wpk, nrm32, cb, Bh, Zf, blockIdx.x);
}

// ---------------------------------------------------------------------------
// K5b v4: gather epilogue, quasiconvex-GELU, 32-point blocks (grid 2352).
// ---------------------------------------------------------------------------
__global__ __launch_bounds__(256) void k_out2(
    const float* __restrict__ e0, const float* __restrict__ gam,
    const float* __restrict__ bet, float* __restrict__ out,
    const unsigned short* __restrict__ Bh, const float* __restrict__ Zf,
    float* __restrict__ e1)
{
    __shared__ int jidx[32 * KNN];
    int blk = blockIdx.x;
    int b   = blk / 588;
    int r   = blk % 588;
    int nt  = r % 98, ot = r / 98;
    int n0 = nt * 32, o0 = ot * 64;
    int tid = threadIdx.x;
    int tx = tid & 15, ty = tid >> 4;

    for (int e = tid; e < 32 * KNN; e += 256)
        jidx[e] = (int)e0[((size_t)b * NPT + n0 + e / KNN) * KNN + e % KNN];

    // e1 tail: 2352 blocks x 48 = 112,896 elements, disjoint slices
    {
        int p = blk * 48 + tid;
        if (tid < 48) e1[p] = (float)((p / KNN) % NPT);
    }

    const float inv_s = 0.9999950000374997f;  // 1/sqrt(1+1e-5)
    float gs[4], bts[4];
#pragma unroll
    for (int v = 0; v < 4; ++v) {
        int o = o0 + tx * 4 + v;
        gs[v]  = gam[o] * inv_s;
        bts[v] = bet[o];
    }
    __syncthreads();

    float best[2][4];
#pragma unroll
    for (int u = 0; u < 2; ++u) {
        int prow = n0 + ty * 2 + u;
        float4 z = *(const float4*)
            &Zf[(size_t)(b * NPT + prow) * 384 + o0 + tx * 4];
        float zA[4] = {z.x, z.y, z.z, z.w};

        float ymin[4], ymax[4];
#pragma unroll
        for (int v = 0; v < 4; ++v) { ymin[v] = 1e30f; ymax[v] = -1e30f; }

        const int* jr = &jidx[(ty * 2 + u) * KNN];
#pragma unroll
        for (int k = 0; k < KNN; ++k) {
            int j = jr[k];
            ushort4 g = *(const ushort4*)
                &Bh[(size_t)(b * NPT + j) * 384 + o0 + tx * 4];
            float bvv[4] = {u2f(g.x), u2f(g.y), u2f(g.z), u2f(g.w)};
#pragma unroll
            for (int v = 0; v < 4; ++v) {
                float y = fmaf(zA[v] + bvv[v], gs[v], bts[v]);
                ymin[v] = fminf(ymin[v], y);
                ymax[v] = fmaxf(ymax[v], y);
            }
        }
#pragma unroll
        for (int v = 0; v < 4; ++v)
            best[u][v] = fmaxf(gelu_exact(ymin[v]), gelu_exact(ymax[v]));
    }

#pragma unroll
    for (int v = 0; v < 4; ++v) {
        int o = o0 + tx * 4 + v;
        float2 pk = {best[0][v], best[1][v]};
        *(float2*)(out + ((size_t)(b * CO_ + o)) * NPT + n0 + ty * 2) = pk;
    }
}

// ---------------------------------------------------------------------------
// K4: B = W2 * x (fallback path, multi-batch).
// ---------------------------------------------------------------------------
__global__ __launch_bounds__(256) void k_gemmB(
    const float* __restrict__ x, const float* __restrict__ cw,
    void* __restrict__ Bq, int bbase, int bcol0, int ldB, int storeBf16,
    int botiles, int bstrideBytes)
{
    int per = 49 * botiles;
    int blk = blockIdx.x;
    int bi  = blk / per;
    int r   = blk % per;
    int b   = bbase + bi;
    int bm = r % 49;
    int bo = r / 49;
    int m0 = bm * 64;
    char* Bp = (char*)Bq + (size_t)bi * (size_t)bstrideBytes;

    __shared__ float Xt[16][68];
    __shared__ float Wt[16][68];
    int tid = threadIdx.x;
    int tx = tid & 15, ty = tid >> 4;
    const float* xb = x + (size_t)b * C_ * NPT;
    float acc[4][4];
#pragma unroll
    for (int u = 0; u < 4; ++u)
#pragma unroll
        for (int v = 0; v < 4; ++v) acc[u][v] = 0.f;

    for (int ct = 0; ct < 12; ++ct) {
        int c0 = ct * 16;
        {
            int cc = tid >> 4, n4 = (tid & 15) * 4;
            *(float4*)&Xt[cc][n4] =
                *(const float4*)&xb[(size_t)(c0 + cc) * NPT + m0 + n4];
        }
        {
            int oo = tid >> 2, c4 = (tid & 3) * 4;
            int o = bcol0 + bo * 64 + oo;
            float4 w = *(const float4*)&cw[(size_t)o * 384 + C_ + c0 + c4];
            Wt[c4 + 0][oo] = w.x; Wt[c4 + 1][oo] = w.y;
            Wt[c4 + 2][oo] = w.z; Wt[c4 + 3][oo] = w.w;
        }
        __syncthreads();
#pragma unroll
        for (int cc = 0; cc < 16; ++cc) {
            float4 av = *(const float4*)&Xt[cc][ty * 4];
            float4 bv = *(const float4*)&Wt[cc][tx * 4];
            float a_[4] = {av.x, av.y, av.z, av.w};
            float b_[4] = {bv.x, bv.y, bv.z, bv.w};
#pragma unroll
            for (int u = 0; u < 4; ++u)
#pragma unroll
                for (int v = 0; v < 4; ++v)
                    acc[u][v] = fmaf(a_[u], b_[v], acc[u][v]);
        }
        __syncthreads();
    }
    if (!storeBf16) {
        float* Bf = (float*)Bp;
#pragma unroll
        for (int u = 0; u < 4; ++u) {
            float4 pk = {acc[u][0], acc[u][1], acc[u][2], acc[u][3]};
            *(float4*)&Bf[(size_t)(m0 + ty * 4 + u) * ldB + bo * 64 + tx * 4] = pk;
        }
    } else {
        unsigned short* Bh = (unsigned short*)Bp;
#pragma unroll
        for (int u = 0; u < 4; ++u) {
            ushort4 pk;
            pk.x = f2u(acc[u][0]); pk.y = f2u(acc[u][1]);
            pk.z = f2u(acc[u][2]); pk.w = f2u(acc[u][3]);
            *(ushort4*)&Bh[(size_t)(m0 + ty * 4 + u) * ldB + bo * 64 + tx * 4] = pk;
        }
    }
}

// ---------------------------------------------------------------------------
// K5: fused epilogue (fallback path, multi-batch). Unchanged (proven).
// ---------------------------------------------------------------------------
__global__ __launch_bounds__(256) void k_outA(
    const float* __restrict__ x, const float* __restrict__ cw,
    const float* __restrict__ e0, const float* __restrict__ cb,
    const float* __restrict__ gam, const float* __restrict__ bet,
    float* __restrict__ out, const void* __restrict__ Bq,
    int bbase, int o0base, int bcol0, int ldB, int readBf16,
    int botiles, int bstrideBytes)
{
    int per = 49 * botiles;
    int blk = blockIdx.x;
    int bi  = blk / per;
    int r   = blk % per;
    int b   = bbase + bi;
    int nt = r % 49, ot = r / 49;
    int n0 = nt * 64, o0 = o0base + ot * 64;
    const char* Bp = (const char*)Bq + (size_t)bi * (size_t)bstrideBytes;

    __shared__ float Xi[16][68];
    __shared__ float Wd[16][68];
    __shared__ int jidx[64 * KNN];
    int tid = threadIdx.x;
    int tx = tid & 15, ty = tid >> 4;
    const float* xb = x + (size_t)b * C_ * NPT;

    for (int e = tid; e < 64 * KNN; e += 256)
        jidx[e] = (int)e0[((size_t)b * NPT + n0 + e / KNN) * KNN + e % KNN];

    float zA[4][4];
#pragma unroll
    for (int u = 0; u < 4; ++u)
#pragma unroll
        for (int v = 0; v < 4; ++v) zA[u][v] = 0.f;

    for (int ct = 0; ct < 12; ++ct) {
        int c0 = ct * 16;
        {
            int cc = tid >> 4, n4 = (tid & 15) * 4;
            *(float4*)&Xi[cc][n4] =
                *(const float4*)&xb[(size_t)(c0 + cc) * NPT + n0 + n4];
        }
        {
            int oo = tid >> 2, c4 = (tid & 3) * 4;
            int o = o0 + oo;
            float4 w1 = *(const float4*)&cw[(size_t)o * 384 + c0 + c4];
            float4 w2 = *(const float4*)&cw[(size_t)o * 384 + C_ + c0 + c4];
            Wd[c4 + 0][oo] = w1.x - w2.x; Wd[c4 + 1][oo] = w1.y - w2.y;
            Wd[c4 + 2][oo] = w1.z - w2.z; Wd[c4 + 3][oo] = w1.w - w2.w;
        }
        __syncthreads();
#pragma unroll
        for (int cc = 0; cc < 16; ++cc) {
            float4 av = *(const float4*)&Xi[cc][ty * 4];
            float4 bv = *(const float4*)&Wd[cc][tx * 4];
            float a_[4] = {av.x, av.y, av.z, av.w};
            float b_[4] = {bv.x, bv.y, bv.z, bv.w};
#pragma unroll
            for (int u = 0; u < 4; ++u)
#pragma unroll
                for (int v = 0; v < 4; ++v)
                    zA[u][v] = fmaf(a_[u], b_[v], zA[u][v]);
        }
        __syncthreads();
    }

    const float inv_s = 0.9999950000374997f;  // 1/sqrt(1+1e-5)
    float gs[4], bts[4], cbs[4];
#pragma unroll
    for (int v = 0; v < 4; ++v) {
        int o = o0 + tx * 4 + v;
        gs[v]  = gam[o] * inv_s;
        bts[v] = bet[o];
        cbs[v] = cb[o];
    }

    float best[4][4];
#pragma unroll
    for (int u = 0; u < 4; ++u)
#pragma unroll
        for (int v = 0; v < 4; ++v) best[u][v] = -1e30f;

    int obB = o0 - bcol0;
    for (int k = 0; k < KNN; ++k) {
#pragma unroll
        for (int u = 0; u < 4; ++u) {
            int j = jidx[(ty * 4 + u) * KNN + k];
            float bvv[4];
            if (!readBf16) {
                float4 g = *(const float4*)
                    ((const float*)Bp + (size_t)j * ldB + obB + tx * 4);
                bvv[0] = g.x; bvv[1] = g.y; bvv[2] = g.z; bvv[3] = g.w;
            } else {
                ushort4 g = *(const ushort4*)
                    ((const unsigned short*)Bp + (size_t)j * ldB + obB + tx * 4);
                bvv[0] = u2f(g.x); bvv[1] = u2f(g.y);
                bvv[2] = u2f(g.z); bvv[3] = u2f(g.w);
            }
#pragma unroll
            for (int v = 0; v < 4; ++v) {
                float z = zA[u][v] + bvv[v] + cbs[v];
                float y = fmaf(z, gs[v], bts[v]);
                float ge = 0.5f * y * (1.0f + erff(y * 0.70710678118654752f));
                best[u][v] = fmaxf(best[u][v], ge);
            }
        }
    }

#pragma unroll
    for (int v = 0; v < 4; ++v) {
        int o = o0 + tx * 4 + v;
        float4 pk = {best[0][v], best[1][v], best[2][v], best[3][v]};
        *(float4*)(out + ((size_t)(b * CO_ + o)) * NPT + n0 + ty * 4) = pk;
    }
}

// ---------------------------------------------------------------------------
// K6: generate edge plane1 (center indices) — fallback paths only.
// ---------------------------------------------------------------------------
__global__ __launch_bounds__(256) void k_center(float* __restrict__ e1)
{
    int p = blockIdx.x * 256 + threadIdx.x;
    if (p >= NROWS * KNN) return;
    e1[p] = (float)((p / KNN) % NPT);
}

// ---------------------------------------------------------------------------
extern "C" void kernel_launch(void* const* d_in, const int* in_sizes, int n_in,
                              void* d_out, int out_size, void* d_ws, size_t ws_size,
                              hipStream_t stream)
{
    const float* x   = (const float*)d_in[0];
    const float* cw  = (const float*)d_in[1];
    const float* cb  = (const float*)d_in[2];
    const float* gam = (const float*)d_in[3];
    const float* bet = (const float*)d_in[4];

    // d_out: FLOAT32. out0 = floats [0, 4,816,896); e0 = [4,816,896,
    // 4,929,792); e1 = [4,929,792, 5,042,688).
    // Scratch liveness (fast path):
    //   invn64 [0, 100,352) | sqd [100,352, 200,704) | invn32 [200,704,
    //   250,880)                                       dead@refine/gemm
    //   cand32 u32 keys  [250,880, 3,462,144)          dead@refine
    //   packed fp16      [3,462,144, 8,279,040)        dead@gemm
    //   nrm32            [8,279,040, 8,329,216)        dead@gemm
    //   wpk              [8,329,216, 8,624,128)        dead@gemm
    //   xT               [9,633,792, 19,267,584)       dead@refine
    // Fused k_refine_gemm hazard audit: refine r{cand32,xT,invn64,sqd}
    //   w{e0}; gemm r{packed,wpk,nrm32,cb} w{Bh,Zf in d_ws} — disjoint;
    //   all gemm inputs written before launch; out2 ordered after.
    float* ou   = (float*)d_out;
    float* out0 = ou;
    double* invn64 = (double*)d_out;
    double* sqd    = (double*)((char*)d_out + 100352);
    float*  invn32 = (float*)((char*)d_out + 200704);
    unsigned* cand32 = (unsigned*)((char*)d_out + 250880);   // 3,211,264 B
    _Float16* packed = (_Float16*)((char*)d_out + 3462144);  // 4,816,896 B
    float*    nrm32  = (float*)((char*)d_out + 8279040);     //    50,176 B
    _Float16* wpk    = (_Float16*)((char*)d_out + 8329216);  //   294,912 B
    float* xT = ou + 2408448;                                // 9.63 MB
    float* e0 = ou + 4816896;
    float* e1 = ou + 4929792;

    const size_t BH_BYTES = (size_t)NROWS * 384 * 2;   //  9,633,792 bf16 B
    const size_t ZF_BYTES = (size_t)NROWS * 384 * 4;   // 19,267,584 fp32 zA
    const int    BSTRIDE  = NPT * CO_ * 4;             // fp32 batch-B stride
    int fastpath = ws_size >= BH_BYTES + ZF_BYTES;

    // norm (196 blocks) + co-dispatched weight pack (72 blocks)
    k_norm <<<196 + 72, 256, 0, stream>>>(x, invn32, invn64, sqd, nrm32,
                                          cw, wpk);
    k_xpose<<<B_ * 6 * 98, 256, 0, stream>>>(x, xT, invn32, packed);

    if (fastpath) {
        // FAST PATH: screen standalone; gemm co-dispatched with refine.
        unsigned short* wsB = (unsigned short*)d_ws;
        float* wsZ = (float*)((char*)d_ws + BH_BYTES);
        k_screen_mfma<<<NSCRB, 256, 0, stream>>>(packed, cand32);
        k_refine_gemm<<<NREFB + 784, 256, 0, stream>>>(
            xT, invn64, sqd, cand32, e0, packed, wpk, nrm32, cb, wsB, wsZ);
        k_out2<<<B_ * 588, 256, 0, stream>>>(e0, gam, bet, out0,
                                             wsB, wsZ, e1);
    } else if (ws_size >= ZF_BYTES) {
        // MEDIUM: all-batch fp32 B in d_ws, fused epilogue.
        k_screen_mfma<<<NSCRB, 256, 0, stream>>>(packed, cand32);
        k_refine<<<NREFB, 256, 0, stream>>>(xT, invn64, sqd, cand32, e0);
        k_gemmB<<<B_ * 49 * 6, 256, 0, stream>>>(
            x, cw, d_ws, 0, 0, 384, 0, 6, BSTRIDE);
        k_outA <<<B_ * 49 * 6, 256, 0, stream>>>(
            x, cw, e0, cb, gam, bet, out0, (const void*)d_ws,
            0, 0, 0, 384, 0, 6, BSTRIDE);
        k_center<<<(NROWS * KNN + 255) / 256, 256, 0, stream>>>(e1);
    } else {
        // FALLBACK: d_out aliasing discipline (R3-proven numerics).
        k_screen_mfma<<<NSCRB, 256, 0, stream>>>(packed, cand32);
        k_refine<<<NREFB, 256, 0, stream>>>(xT, invn64, sqd, cand32, e0);
        k_gemmB<<<2 * 49 * 6, 256, 0, stream>>>(
            x, cw, (void*)ou, 2, 0, 384, 0, 6, BSTRIDE);
        k_outA <<<2 * 49 * 6, 256, 0, stream>>>(
            x, cw, e0, cb, gam, bet, out0, (const void*)ou,
            2, 0, 0, 384, 0, 6, BSTRIDE);
        k_gemmB<<<49 * 6, 256, 0, stream>>>(
            x, cw, (void*)ou, 1, 0, 384, 0, 6, 0);
        k_outA <<<49 * 6, 256, 0, stream>>>(
            x, cw, e0, cb, gam, bet, out0, (const void*)ou,
            1, 0, 0, 384, 0, 6, 0);
        k_gemmB<<<49 * 3, 256, 0, stream>>>(
            x, cw, (void*)ou, 0, 192, 192, 1, 3, 0);
        k_outA <<<49 * 3, 256, 0, stream>>>(
            x, cw, e0, cb, gam, bet, out0, (const void*)ou,
            0, 192, 192, 192, 1, 3, 0);
        k_gemmB<<<49 * 2, 256, 0, stream>>>(
            x, cw, (void*)ou, 0, 64, 128, 1, 2, 0);
        k_outA <<<49 * 2, 256, 0, stream>>>(
            x, cw, e0, cb, gam, bet, out0, (const void*)ou,
            0, 64, 64, 128, 1, 2, 0);
        k_gemmB<<<49 * 1, 256, 0, stream>>>(
            x, cw, (void*)e1, 0, 0, 64, 1, 1, 0);
        k_outA <<<49 * 1, 256, 0, stream>>>(
            x, cw, e0, cb, gam, bet, out0, (const void*)e1,
            0, 0, 0, 64, 1, 1, 0);
        k_center<<<(NROWS * KNN + 255) / 256, 256, 0, stream>>>(e1);
    }
}

// Round 19
// 167.017 us; speedup vs baseline: 1.0428x; 1.0428x over previous
//
#include <hip/hip_runtime.h>
#include <hip/hip_bf16.h>
#include <math.h>

#define B_    4
#define C_    192
#define NPT   3136          // H*W points per batch
#define CO_   384           // Cout
#define KNN   9
#define K2    16            // exact-refine set size (approx-top-16 of 63)
#define NROWS (B_*NPT)      // 12544 total points
#define SD    10            // per-list screening depth
#define NSCRB (7*196)       // screen blocks in fused launch

typedef _Float16 half8 __attribute__((ext_vector_type(8)));
typedef float    f32x4 __attribute__((ext_vector_type(4)));

__device__ __forceinline__ float u2f(unsigned short u) {
    unsigned int t = ((unsigned int)u) << 16;
    float f; __builtin_memcpy(&f, &t, 4); return f;
}
__device__ __forceinline__ unsigned short f2u(float f) {
    __hip_bfloat16 h = __float2bfloat16(f);
    unsigned short u; __builtin_memcpy(&u, &h, 2); return u;
}
__device__ __forceinline__ float gelu_exact(float y) {
    return 0.5f * y * (1.0f + erff(y * 0.70710678118654752f));
}
// sortable u64 key for an f64 (ascending double order == ascending u64 order)
__device__ __forceinline__ unsigned long long dkey(double d) {
    long long sb = __double_as_longlong(d);
    unsigned long long u = (unsigned long long)sb;
    return (sb < 0) ? ~u : (u | 0x8000000000000000ULL);
}

// ---------------------------------------------------------------------------
// K1 v5: per-point f64 norm stats (+ fp32 norm) with co-dispatched weight
//   pack (blocks >= 196; verbatim k_wpack body; disjoint outputs).
// ---------------------------------------------------------------------------
__global__ __launch_bounds__(256) void k_norm(
    const float* __restrict__ x,
    float* __restrict__ invn32, double* __restrict__ invn64,
    double* __restrict__ sqd, float* __restrict__ nrm32,
    const float* __restrict__ cw, _Float16* __restrict__ wpk)
{
    __shared__ double part[4][64];
    if (blockIdx.x >= 196) {            // weight-pack blocks (72)
        int t = (blockIdx.x - 196) * 256 + threadIdx.x;  // 0..18431
        int l  = t & 63;
        int tk = t >> 6;                // ot*6+kk
        int kk = tk % 6, ot = tk / 6;
        int hsel = ot / 24;
        int o = (ot % 24) * 16 + (l & 15);
        int k = kk * 32 + (l >> 4) * 8;
        half8 h;
#pragma unroll
        for (int e = 0; e < 8; ++e) {
            float w2 = cw[(size_t)o * 384 + C_ + k + e];
            float wv = hsel ? w2 : (cw[(size_t)o * 384 + k + e] - w2);
            h[e] = (_Float16)wv;
        }
        *(half8*)(wpk + (size_t)t * 8) = h;
        return;
    }
    int wave = threadIdx.x >> 6, lane = threadIdx.x & 63;
    int p0 = blockIdx.x * 64;          // 64 points per block, 196 blocks
    int row = p0 + lane;
    int b = row / NPT, n = row % NPT;
    const float* xb = x + (size_t)b * C_ * NPT + n;
    double S = 0.0;
    int c0 = wave * 48;
    for (int c = c0; c < c0 + 48; ++c) {
        double v = (double)xb[(size_t)c * NPT];
        S = fma(v, v, S);
    }
    part[wave][lane] = S;
    __syncthreads();
    if (threadIdx.x < 64) {
        double T = ((part[0][lane] + part[1][lane]) + part[2][lane])
                 + part[3][lane];
        double nrm = sqrt(T);
        if (nrm < 1e-12) nrm = 1e-12;
        double iv = 1.0 / nrm;
        int prow = p0 + lane;
        invn64[prow] = iv;
        invn32[prow] = (float)iv;
        sqd[prow] = iv * iv * T;
        nrm32[prow] = (float)nrm;
    }
}

// ---------------------------------------------------------------------------
// K1b v2: LDS-tiled transpose x -> xT (fp32, exact) + fused fp16 pack.
// ---------------------------------------------------------------------------
__global__ __launch_bounds__(256) void k_xpose(
    const float* __restrict__ x, float* __restrict__ xT,
    const float* __restrict__ invn32, _Float16* __restrict__ packed)
{
    __shared__ float t[32][33];
    int blk = blockIdx.x;
    int b  = blk / 588;
    int r  = blk % 588;
    int ct = r / 98, nt = r % 98;
    int c0 = ct * 32, n0 = nt * 32;
    int tid = threadIdx.x;
    int tx = tid & 31, ty8 = tid >> 5;          // 8 rows per pass
    const float* xb = x + (size_t)b * C_ * NPT;
#pragma unroll
    for (int e = 0; e < 4; ++e) {
        int cc = ty8 + e * 8;
        t[cc][tx] = xb[(size_t)(c0 + cc) * NPT + n0 + tx];
    }
    __syncthreads();
#pragma unroll
    for (int e = 0; e < 4; ++e) {
        int nn = ty8 + e * 8;
        xT[(size_t)(b * NPT + n0 + nn) * C_ + c0 + tx] = t[tx][nn];
    }
    if (tid < 128) {
        int f = tid >> 6, l = tid & 63;
        int pt = f * 16 + (l & 15);            // tile-local point
        float iv = invn32[(size_t)b * NPT + n0 + pt];
        int cb = (l >> 4) * 8;                 // tile-local channel base
        half8 h;
#pragma unroll
        for (int e = 0; e < 8; ++e)
            h[e] = (_Float16)(t[cb + e][pt] * iv);
        size_t idx = ((((size_t)(b * 196 + nt * 2 + f)) * 6 + ct) * 64 + l) * 8;
        *(half8*)(packed + idx) = h;
    }
}

// ---------------------------------------------------------------------------
// dev_screen: MFMA v5 screening body, transposed md[80][64] (20,480 B).
//   Reads md[s][tid]: bank = tid%32 -> 2 lanes/bank (free). Writes
//   md[stream][ir]: 4-way, but only 20 writes per block lifetime.
// ---------------------------------------------------------------------------
__device__ __forceinline__ void dev_screen(
    unsigned (*md)[64],
    const _Float16* __restrict__ packed, unsigned* __restrict__ cand,
    int blk)
{
    int chunk = blk / 196;               // 0..6
    int t2    = blk % 196;
    int b     = t2 / 49;
    int itile = t2 % 49;                 // 64-row i tile
    int tid   = threadIdx.x;
    int wave  = tid >> 6, lane = tid & 63;
    int it    = itile * 4 + wave;        // global 16-row tile within batch

    const _Float16* pb = packed + ((size_t)(b * 196 + it) * 6) * 512 + lane * 8;
    half8 bf[6];
#pragma unroll
    for (int kk = 0; kk < 6; ++kk)
        bf[kk] = *(const half8*)(pb + kk * 512);

    int jt0 = chunk * 28;                 // 7 chunks x 28 tiles (uniform)
    const int ntj = 28;

    unsigned bdA[SD], bdB[SD];
#pragma unroll
    for (int q = 0; q < SD; ++q) { bdA[q] = 0u; bdB[q] = 0u; }

    const _Float16* pa_base =
        packed + ((size_t)(b * 196 + jt0) * 6) * 512 + lane * 8;

    half8 af[6];
#pragma unroll
    for (int kk = 0; kk < 6; ++kk)
        af[kk] = *(const half8*)(pa_base + kk * 512);

    for (int jt = 0; jt < ntj; ++jt) {
        f32x4 acc = {0.f, 0.f, 0.f, 0.f};
#pragma unroll
        for (int kk = 0; kk < 6; ++kk)
            acc = __builtin_amdgcn_mfma_f32_16x16x32_f16(af[kk], bf[kk], acc, 0, 0, 0);

        if (jt + 1 < ntj) {
            const _Float16* pn = pa_base + (size_t)(jt + 1) * 6 * 512;
#pragma unroll
            for (int kk = 0; kk < 6; ++kk)
                af[kk] = *(const half8*)(pn + kk * 512);
        }

        unsigned jb = (unsigned)((jt0 + jt) * 16 + (lane >> 4) * 4);
        // list A: acc[0], acc[1]   (independent chain from list B)
#pragma unroll
        for (int q = 0; q < 2; ++q) {
            unsigned fb = __float_as_uint(acc[q] + 2.0f);
            unsigned c = (fb & 0xFFFFF000u) | (jb + (unsigned)q);
#pragma unroll
            for (int t = 0; t < SD; ++t) {
                unsigned old = bdA[t];
                unsigned mx = old > c ? old : c;
                c           = old > c ? c : old;
                bdA[t] = mx;
            }
        }
        // list B: acc[2], acc[3]
#pragma unroll
        for (int q = 2; q < 4; ++q) {
            unsigned fb = __float_as_uint(acc[q] + 2.0f);
            unsigned c = (fb & 0xFFFFF000u) | (jb + (unsigned)q);
#pragma unroll
            for (int t = 0; t < SD; ++t) {
                unsigned old = bdB[t];
                unsigned mx = old > c ? old : c;
                c           = old > c ? c : old;
                bdB[t] = mx;
            }
        }
    }

    int ir = wave * 16 + (lane & 15);    // i-row within block (0..63)
    int g  = lane >> 4;                  // lane group -> streams 2g, 2g+1
#pragma unroll
    for (int q = 0; q < SD; ++q) {
        md[(g * 2 + 0) * SD + q][ir] = bdA[q];
        md[(g * 2 + 1) * SD + q][ir] = bdB[q];
    }
    __syncthreads();

    if (tid < 64) {
        int h[8] = {0, 0, 0, 0, 0, 0, 0, 0};
        size_t rowi = (size_t)b * NPT + itile * 64 + tid;
        unsigned* cp = cand + rowi * 64 + chunk * 9;
        const unsigned* rd = &md[0][tid];
        for (int s = 0; s < 9; ++s) {
            unsigned best = 0u; int bg = 0;
#pragma unroll
            for (int g2 = 0; g2 < 8; ++g2) {
                unsigned v = (h[g2] < SD) ? rd[(g2 * SD + h[g2]) * 64] : 0u;
                if (v > best) { best = v; bg = g2; }
            }
            cp[s] = best;
            h[bg]++;
        }
        if (chunk == 0)                   // sentinel slot 63: key 0
            cand[rowi * 64 + 63] = 0u;
    }
}

// ---------------------------------------------------------------------------
// dev_gemm: MFMA dual-GEMM body (proven R12/R14/R15 code, verbatim).
// ---------------------------------------------------------------------------
__device__ __forceinline__ void dev_gemm(
    const _Float16* __restrict__ packed, const _Float16* __restrict__ wpk,
    const float* __restrict__ nrm32, const float* __restrict__ cb,
    unsigned short* __restrict__ Bh, float* __restrict__ Zf, int pt)
{
    int wave = threadIdx.x >> 6, lane = threadIdx.x & 63;
    int hsel = wave >> 1;               // 0: Zf, 1: Bh
    int og   = wave & 1;                // o half within 384

    const _Float16* px = packed + (size_t)pt * 6 * 512 + lane * 8;
    half8 pf[6];
#pragma unroll
    for (int kk = 0; kk < 6; ++kk) pf[kk] = *(const half8*)(px + kk * 512);

    float s = nrm32[pt * 16 + (lane & 15)];
    size_t row0 = (size_t)pt * 16 + (lane & 15);
    int olane = (lane >> 4) * 4;

    int ot0 = hsel * 24 + og * 12;
    const _Float16* wb = wpk + (size_t)ot0 * 6 * 512 + lane * 8;

    half8 wf[6];
#pragma unroll
    for (int kk = 0; kk < 6; ++kk) wf[kk] = *(const half8*)(wb + kk * 512);

    for (int t = 0; t < 12; ++t) {
        f32x4 acc = {0.f, 0.f, 0.f, 0.f};
#pragma unroll
        for (int kk = 0; kk < 6; ++kk)
            acc = __builtin_amdgcn_mfma_f32_16x16x32_f16(wf[kk], pf[kk], acc, 0, 0, 0);

        if (t < 11) {
            const _Float16* wn = wb + (size_t)(t + 1) * 6 * 512;
#pragma unroll
            for (int kk = 0; kk < 6; ++kk)
                wf[kk] = *(const half8*)(wn + kk * 512);
        }

        int o = (og * 12 + t) * 16 + olane;
        if (hsel == 0) {
            float4 cbv = *(const float4*)&cb[o];
            float4 zv;
            zv.x = acc[0] * s + cbv.x; zv.y = acc[1] * s + cbv.y;
            zv.z = acc[2] * s + cbv.z; zv.w = acc[3] * s + cbv.w;
            *(float4*)&Zf[row0 * 384 + o] = zv;
        } else {
            ushort4 pk;
            pk.x = f2u(acc[0] * s); pk.y = f2u(acc[1] * s);
            pk.z = f2u(acc[2] * s); pk.w = f2u(acc[3] * s);
            *(ushort4*)&Bh[row0 * 384 + o] = pk;
        }
    }
}

// ---------------------------------------------------------------------------
// K2: standalone screen (medium/fallback paths).
// ---------------------------------------------------------------------------
__global__ __launch_bounds__(256) void k_screen_mfma(
    const _Float16* __restrict__ packed, unsigned* __restrict__ cand)
{
    __shared__ unsigned md[8 * SD][64];   // 20,480 B
    dev_screen(md, packed, cand, blockIdx.x);
}

// ---------------------------------------------------------------------------
// K2g: FUSED screen + gemm co-dispatch (fast path).
// ---------------------------------------------------------------------------
__global__ __launch_bounds__(256) void k_screen_gemm(
    const _Float16* __restrict__ packed, unsigned* __restrict__ cand,
    const _Float16* __restrict__ wpk, const float* __restrict__ nrm32,
    const float* __restrict__ cb,
    unsigned short* __restrict__ Bh, float* __restrict__ Zf)
{
    __shared__ unsigned md[8 * SD][64];   // 20,480 B -> 8 blocks/CU
    if (blockIdx.x < NSCRB)
        dev_screen(md, packed, cand, blockIdx.x);
    else
        dev_gemm(packed, wpk, nrm32, cb, Bh, Zf, blockIdx.x - NSCRB);
}

// ---------------------------------------------------------------------------
// K3 v7: key-merge + exact f64 refine on approx-top-K2 (=16) only.
// ---------------------------------------------------------------------------
__global__ __launch_bounds__(256) void k_refine(
    const float* __restrict__ xT, const double* __restrict__ invn64,
    const double* __restrict__ sqd, const unsigned* __restrict__ cand32,
    float* __restrict__ e0)
{
    __shared__ unsigned km[4][64];
    __shared__ int    icand[4][K2];
    __shared__ double civ[4][K2];
    __shared__ double csq[4][K2];
    __shared__ unsigned long long kbuf[4][K2];
    __shared__ float  xi[4][C_];
    int wave = threadIdx.x >> 6;
    int lane = threadIdx.x & 63;
    int row  = blockIdx.x * 4 + wave;
    int b    = row / NPT;
    size_t bN = (size_t)b * NPT;

    unsigned kc = cand32[(size_t)row * 64 + lane];
    km[wave][lane] = kc;
    const float* xiRow = xT + (size_t)row * C_;
    xi[wave][lane]       = xiRow[lane];
    xi[wave][lane + 64]  = xiRow[lane + 64];
    xi[wave][lane + 128] = xiRow[lane + 128];
    __syncthreads();

    // approx rank (descending key); keys distinct -> permutation 0..63
    int keyrank = 0;
#pragma unroll
    for (int m = 0; m < 64; ++m)
        keyrank += (km[wave][m] > kc) ? 1 : 0;
    if (keyrank < K2)
        icand[wave][keyrank] = (int)(kc & 0xFFFu);
    __syncthreads();
    if (lane < K2) {
        int j = icand[wave][lane];
        civ[wave][lane] = invn64[bN + j];
        csq[wave][lane] = sqd[bN + j];
    }
    __syncthreads();

    int sub = lane & 7, cg = lane >> 3;
    double ivi = invn64[row], sqi = sqd[row];
    const float* xw = &xi[wave][sub * 4];

    // prologue: first half of candidate cg
    float4 h0a, h0b, h0c;
    {
        int j0 = icand[wave][cg];
        const float* p = xT + (bN + j0) * C_ + sub * 4;
        h0a = *(const float4*)&p[0];
        h0b = *(const float4*)&p[32];
        h0c = *(const float4*)&p[64];
    }

#pragma unroll
    for (int cc = 0; cc < K2 / 8; ++cc) {
        int cidx = cc * 8 + cg;
        int jcur = icand[wave][cidx];
        const float* pc = xT + (bN + jcur) * C_ + sub * 4;
        float4 h1a = *(const float4*)&pc[96];
        float4 h1b = *(const float4*)&pc[128];
        float4 h1c = *(const float4*)&pc[160];

        double d0 = 0.0, d1 = 0.0, d2 = 0.0, d3 = 0.0;
        {
            float4 xq;
            xq = *(const float4*)&xw[0];
            d0 = fma((double)xq.x, (double)h0a.x, d0);
            d1 = fma((double)xq.y, (double)h0a.y, d1);
            d2 = fma((double)xq.z, (double)h0a.z, d2);
            d3 = fma((double)xq.w, (double)h0a.w, d3);
            xq = *(const float4*)&xw[32];
            d0 = fma((double)xq.x, (double)h0b.x, d0);
            d1 = fma((double)xq.y, (double)h0b.y, d1);
            d2 = fma((double)xq.z, (double)h0b.z, d2);
            d3 = fma((double)xq.w, (double)h0b.w, d3);
            xq = *(const float4*)&xw[64];
            d0 = fma((double)xq.x, (double)h0c.x, d0);
            d1 = fma((double)xq.y, (double)h0c.y, d1);
            d2 = fma((double)xq.z, (double)h0c.z, d2);
            d3 = fma((double)xq.w, (double)h0c.w, d3);
        }
        if (cc < K2 / 8 - 1) {
            int jn = icand[wave][cidx + 8];
            const float* pn = xT + (bN + jn) * C_ + sub * 4;
            h0a = *(const float4*)&pn[0];
            h0b = *(const float4*)&pn[32];
            h0c = *(const float4*)&pn[64];
        }
        {
            float4 xq;
            xq = *(const float4*)&xw[96];
            d0 = fma((double)xq.x, (double)h1a.x, d0);
            d1 = fma((double)xq.y, (double)h1a.y, d1);
            d2 = fma((double)xq.z, (double)h1a.z, d2);
            d3 = fma((double)xq.w, (double)h1a.w, d3);
            xq = *(const float4*)&xw[128];
            d0 = fma((double)xq.x, (double)h1b.x, d0);
            d1 = fma((double)xq.y, (double)h1b.y, d1);
            d2 = fma((double)xq.z, (double)h1b.z, d2);
            d3 = fma((double)xq.w, (double)h1b.w, d3);
            xq = *(const float4*)&xw[160];
            d0 = fma((double)xq.x, (double)h1c.x, d0);
            d1 = fma((double)xq.y, (double)h1c.y, d1);
            d2 = fma((double)xq.z, (double)h1c.z, d2);
            d3 = fma((double)xq.w, (double)h1c.w, d3);
        }
        double dot = (d0 + d1) + (d2 + d3);
        dot += __shfl_xor(dot, 1);
        dot += __shfl_xor(dot, 2);
        dot += __shfl_xor(dot, 4);
        if (sub == 0) {
            double dist = sqi + csq[wave][cidx]
                        - 2.0 * (ivi * civ[wave][cidx] * dot);
            kbuf[wave][cidx] = dkey(dist);
        }
    }
    __syncthreads();

    // exact rank-based top-9 over the K2 refined candidates
    if (lane < K2) {
        unsigned long long kd = kbuf[wave][lane];
        int jme = icand[wave][lane];
        int rank = 0;
#pragma unroll
        for (int m = 0; m < K2; ++m) {
            unsigned long long km2 = kbuf[wave][m];
            int jm = icand[wave][m];
            rank += ((km2 < kd) || (km2 == kd && jm < jme)) ? 1 : 0;
        }
        if (rank < KNN)
            e0[(size_t)row * KNN + rank] = (float)jme;
    }
}

// ---------------------------------------------------------------------------
// K5b v4: gather epilogue, quasiconvex-GELU, 32-point blocks (grid 2352).
// ---------------------------------------------------------------------------
__global__ __launch_bounds__(256) void k_out2(
    const float* __restrict__ e0, const float* __restrict__ gam,
    const float* __restrict__ bet, float* __restrict__ out,
    const unsigned short* __restrict__ Bh, const float* __restrict__ Zf,
    float* __restrict__ e1)
{
    __shared__ int jidx[32 * KNN];
    int blk = blockIdx.x;
    int b   = blk / 588;
    int r   = blk % 588;
    int nt  = r % 98, ot = r / 98;
    int n0 = nt * 32, o0 = ot * 64;
    int tid = threadIdx.x;
    int tx = tid & 15, ty = tid >> 4;

    for (int e = tid; e < 32 * KNN; e += 256)
        jidx[e] = (int)e0[((size_t)b * NPT + n0 + e / KNN) * KNN + e % KNN];

    // e1 tail: 2352 blocks x 48 = 112,896 elements, disjoint slices
    {
        int p = blk * 48 + tid;
        if (tid < 48) e1[p] = (float)((p / KNN) % NPT);
    }

    const float inv_s = 0.9999950000374997f;  // 1/sqrt(1+1e-5)
    float gs[4], bts[4];
#pragma unroll
    for (int v = 0; v < 4; ++v) {
        int o = o0 + tx * 4 + v;
        gs[v]  = gam[o] * inv_s;
        bts[v] = bet[o];
    }
    __syncthreads();

    float best[2][4];
#pragma unroll
    for (int u = 0; u < 2; ++u) {
        int prow = n0 + ty * 2 + u;
        float4 z = *(const float4*)
            &Zf[(size_t)(b * NPT + prow) * 384 + o0 + tx * 4];
        float zA[4] = {z.x, z.y, z.z, z.w};

        float ymin[4], ymax[4];
#pragma unroll
        for (int v = 0; v < 4; ++v) { ymin[v] = 1e30f; ymax[v] = -1e30f; }

        const int* jr = &jidx[(ty * 2 + u) * KNN];
#pragma unroll
        for (int k = 0; k < KNN; ++k) {
            int j = jr[k];
            ushort4 g = *(const ushort4*)
                &Bh[(size_t)(b * NPT + j) * 384 + o0 + tx * 4];
            float bvv[4] = {u2f(g.x), u2f(g.y), u2f(g.z), u2f(g.w)};
#pragma unroll
            for (int v = 0; v < 4; ++v) {
                float y = fmaf(zA[v] + bvv[v], gs[v], bts[v]);
                ymin[v] = fminf(ymin[v], y);
                ymax[v] = fmaxf(ymax[v], y);
            }
        }
#pragma unroll
        for (int v = 0; v < 4; ++v)
            best[u][v] = fmaxf(gelu_exact(ymin[v]), gelu_exact(ymax[v]));
    }

#pragma unroll
    for (int v = 0; v < 4; ++v) {
        int o = o0 + tx * 4 + v;
        float2 pk = {best[0][v], best[1][v]};
        *(float2*)(out + ((size_t)(b * CO_ + o)) * NPT + n0 + ty * 2) = pk;
    }
}

// ---------------------------------------------------------------------------
// K4: B = W2 * x (fallback path, multi-batch).
// ---------------------------------------------------------------------------
__global__ __launch_bounds__(256) void k_gemmB(
    const float* __restrict__ x, const float* __restrict__ cw,
    void* __restrict__ Bq, int bbase, int bcol0, int ldB, int storeBf16,
    int botiles, int bstrideBytes)
{
    int per = 49 * botiles;
    int blk = blockIdx.x;
    int bi  = blk / per;
    int r   = blk % per;
    int b   = bbase + bi;
    int bm = r % 49;
    int bo = r / 49;
    int m0 = bm * 64;
    char* Bp = (char*)Bq + (size_t)bi * (size_t)bstrideBytes;

    __shared__ float Xt[16][68];
    __shared__ float Wt[16][68];
    int tid = threadIdx.x;
    int tx = tid & 15, ty = tid >> 4;
    const float* xb = x + (size_t)b * C_ * NPT;
    float acc[4][4];
#pragma unroll
    for (int u = 0; u < 4; ++u)
#pragma unroll
        for (int v = 0; v < 4; ++v) acc[u][v] = 0.f;

    for (int ct = 0; ct < 12; ++ct) {
        int c0 = ct * 16;
        {
            int cc = tid >> 4, n4 = (tid & 15) * 4;
            *(float4*)&Xt[cc][n4] =
                *(const float4*)&xb[(size_t)(c0 + cc) * NPT + m0 + n4];
        }
        {
            int oo = tid >> 2, c4 = (tid & 3) * 4;
            int o = bcol0 + bo * 64 + oo;
            float4 w = *(const float4*)&cw[(size_t)o * 384 + C_ + c0 + c4];
            Wt[c4 + 0][oo] = w.x; Wt[c4 + 1][oo] = w.y;
            Wt[c4 + 2][oo] = w.z; Wt[c4 + 3][oo] = w.w;
        }
        __syncthreads();
#pragma unroll
        for (int cc = 0; cc < 16; ++cc) {
            float4 av = *(const float4*)&Xt[cc][ty * 4];
            float4 bv = *(const float4*)&Wt[cc][tx * 4];
            float a_[4] = {av.x, av.y, av.z, av.w};
            float b_[4] = {bv.x, bv.y, bv.z, bv.w};
#pragma unroll
            for (int u = 0; u < 4; ++u)
#pragma unroll
                for (int v = 0; v < 4; ++v)
                    acc[u][v] = fmaf(a_[u], b_[v], acc[u][v]);
        }
        __syncthreads();
    }
    if (!storeBf16) {
        float* Bf = (float*)Bp;
#pragma unroll
        for (int u = 0; u < 4; ++u) {
            float4 pk = {acc[u][0], acc[u][1], acc[u][2], acc[u][3]};
            *(float4*)&Bf[(size_t)(m0 + ty * 4 + u) * ldB + bo * 64 + tx * 4] = pk;
        }
    } else {
        unsigned short* Bh = (unsigned short*)Bp;
#pragma unroll
        for (int u = 0; u < 4; ++u) {
            ushort4 pk;
            pk.x = f2u(acc[u][0]); pk.y = f2u(acc[u][1]);
            pk.z = f2u(acc[u][2]); pk.w = f2u(acc[u][3]);
            *(ushort4*)&Bh[(size_t)(m0 + ty * 4 + u) * ldB + bo * 64 + tx * 4] = pk;
        }
    }
}

// ---------------------------------------------------------------------------
// K5: fused epilogue (fallback path, multi-batch). Unchanged (proven).
// ---------------------------------------------------------------------------
__global__ __launch_bounds__(256) void k_outA(
    const float* __restrict__ x, const float* __restrict__ cw,
    const float* __restrict__ e0, const float* __restrict__ cb,
    const float* __restrict__ gam, const float* __restrict__ bet,
    float* __restrict__ out, const void* __restrict__ Bq,
    int bbase, int o0base, int bcol0, int ldB, int readBf16,
    int botiles, int bstrideBytes)
{
    int per = 49 * botiles;
    int blk = blockIdx.x;
    int bi  = blk / per;
    int r   = blk % per;
    int b   = bbase + bi;
    int nt = r % 49, ot = r / 49;
    int n0 = nt * 64, o0 = o0base + ot * 64;
    const char* Bp = (const char*)Bq + (size_t)bi * (size_t)bstrideBytes;

    __shared__ float Xi[16][68];
    __shared__ float Wd[16][68];
    __shared__ int jidx[64 * KNN];
    int tid = threadIdx.x;
    int tx = tid & 15, ty = tid >> 4;
    const float* xb = x + (size_t)b * C_ * NPT;

    for (int e = tid; e < 64 * KNN; e += 256)
        jidx[e] = (int)e0[((size_t)b * NPT + n0 + e / KNN) * KNN + e % KNN];

    float zA[4][4];
#pragma unroll
    for (int u = 0; u < 4; ++u)
#pragma unroll
        for (int v = 0; v < 4; ++v) zA[u][v] = 0.f;

    for (int ct = 0; ct < 12; ++ct) {
        int c0 = ct * 16;
        {
            int cc = tid >> 4, n4 = (tid & 15) * 4;
            *(float4*)&Xi[cc][n4] =
                *(const float4*)&xb[(size_t)(c0 + cc) * NPT + n0 + n4];
        }
        {
            int oo = tid >> 2, c4 = (tid & 3) * 4;
            int o = o0 + oo;
            float4 w1 = *(const float4*)&cw[(size_t)o * 384 + c0 + c4];
            float4 w2 = *(const float4*)&cw[(size_t)o * 384 + C_ + c0 + c4];
            Wd[c4 + 0][oo] = w1.x - w2.x; Wd[c4 + 1][oo] = w1.y - w2.y;
            Wd[c4 + 2][oo] = w1.z - w2.z; Wd[c4 + 3][oo] = w1.w - w2.w;
        }
        __syncthreads();
#pragma unroll
        for (int cc = 0; cc < 16; ++cc) {
            float4 av = *(const float4*)&Xi[cc][ty * 4];
            float4 bv = *(const float4*)&Wd[cc][tx * 4];
            float a_[4] = {av.x, av.y, av.z, av.w};
            float b_[4] = {bv.x, bv.y, bv.z, bv.w};
#pragma unroll
            for (int u = 0; u < 4; ++u)
#pragma unroll
                for (int v = 0; v < 4; ++v)
                    zA[u][v] = fmaf(a_[u], b_[v], zA[u][v]);
        }
        __syncthreads();
    }

    const float inv_s = 0.9999950000374997f;  // 1/sqrt(1+1e-5)
    float gs[4], bts[4], cbs[4];
#pragma unroll
    for (int v = 0; v < 4; ++v) {
        int o = o0 + tx * 4 + v;
        gs[v]  = gam[o] * inv_s;
        bts[v] = bet[o];
        cbs[v] = cb[o];
    }

    float best[4][4];
#pragma unroll
    for (int u = 0; u < 4; ++u)
#pragma unroll
        for (int v = 0; v < 4; ++v) best[u][v] = -1e30f;

    int obB = o0 - bcol0;
    for (int k = 0; k < KNN; ++k) {
#pragma unroll
        for (int u = 0; u < 4; ++u) {
            int j = jidx[(ty * 4 + u) * KNN + k];
            float bvv[4];
            if (!readBf16) {
                float4 g = *(const float4*)
                    ((const float*)Bp + (size_t)j * ldB + obB + tx * 4);
                bvv[0] = g.x; bvv[1] = g.y; bvv[2] = g.z; bvv[3] = g.w;
            } else {
                ushort4 g = *(const ushort4*)
                    ((const unsigned short*)Bp + (size_t)j * ldB + obB + tx * 4);
                bvv[0] = u2f(g.x); bvv[1] = u2f(g.y);
                bvv[2] = u2f(g.z); bvv[3] = u2f(g.w);
            }
#pragma unroll
            for (int v = 0; v < 4; ++v) {
                float z = zA[u][v] + bvv[v] + cbs[v];
                float y = fmaf(z, gs[v], bts[v]);
                float ge = 0.5f * y * (1.0f + erff(y * 0.70710678118654752f));
                best[u][v] = fmaxf(best[u][v], ge);
            }
        }
    }

#pragma unroll
    for (int v = 0; v < 4; ++v) {
        int o = o0 + tx * 4 + v;
        float4 pk = {best[0][v], best[1][v], best[2][v], best[3][v]};
        *(float4*)(out + ((size_t)(b * CO_ + o)) * NPT + n0 + ty * 4) = pk;
    }
}

// ---------------------------------------------------------------------------
// K6: generate edge plane1 (center indices) — fallback paths only.
// ---------------------------------------------------------------------------
__global__ __launch_bounds__(256) void k_center(float* __restrict__ e1)
{
    int p = blockIdx.x * 256 + threadIdx.x;
    if (p >= NROWS * KNN) return;
    e1[p] = (float)((p / KNN) % NPT);
}

// ---------------------------------------------------------------------------
extern "C" void kernel_launch(void* const* d_in, const int* in_sizes, int n_in,
                              void* d_out, int out_size, void* d_ws, size_t ws_size,
                              hipStream_t stream)
{
    const float* x   = (const float*)d_in[0];
    const float* cw  = (const float*)d_in[1];
    const float* cb  = (const float*)d_in[2];
    const float* gam = (const float*)d_in[3];
    const float* bet = (const float*)d_in[4];

    // d_out: FLOAT32. out0 = floats [0, 4,816,896); e0 = [4,816,896,
    // 4,929,792); e1 = [4,929,792, 5,042,688).
    // Scratch liveness (fast path):
    //   invn64 [0, 100,352) | sqd [100,352, 200,704) | invn32 [200,704,
    //   250,880)                                       dead@refine/gemm
    //   cand32 u32 keys  [250,880, 3,462,144)          dead@refine
    //   packed fp16      [3,462,144, 8,279,040)        dead@gemm
    //   nrm32            [8,279,040, 8,329,216)        dead@gemm
    //   wpk              [8,329,216, 8,624,128)        dead@gemm
    //   xT               [9,633,792, 19,267,584)       dead@refine
    float* ou   = (float*)d_out;
    float* out0 = ou;
    double* invn64 = (double*)d_out;
    double* sqd    = (double*)((char*)d_out + 100352);
    float*  invn32 = (float*)((char*)d_out + 200704);
    unsigned* cand32 = (unsigned*)((char*)d_out + 250880);   // 3,211,264 B
    _Float16* packed = (_Float16*)((char*)d_out + 3462144);  // 4,816,896 B
    float*    nrm32  = (float*)((char*)d_out + 8279040);     //    50,176 B
    _Float16* wpk    = (_Float16*)((char*)d_out + 8329216);  //   294,912 B
    float* xT = ou + 2408448;                                // 9.63 MB
    float* e0 = ou + 4816896;
    float* e1 = ou + 4929792;

    const size_t BH_BYTES = (size_t)NROWS * 384 * 2;   //  9,633,792 bf16 B
    const size_t ZF_BYTES = (size_t)NROWS * 384 * 4;   // 19,267,584 fp32 zA
    const int    BSTRIDE  = NPT * CO_ * 4;             // fp32 batch-B stride
    int fastpath = ws_size >= BH_BYTES + ZF_BYTES;

    // norm (196 blocks) + co-dispatched weight pack (72 blocks)
    k_norm <<<196 + 72, 256, 0, stream>>>(x, invn32, invn64, sqd, nrm32,
                                          cw, wpk);
    k_xpose<<<B_ * 6 * 98, 256, 0, stream>>>(x, xT, invn32, packed);

    if (fastpath) {
        // FAST PATH: screen co-dispatched with MFMA dual GEMM.
        unsigned short* wsB = (unsigned short*)d_ws;
        float* wsZ = (float*)((char*)d_ws + BH_BYTES);
        k_screen_gemm<<<NSCRB + 784, 256, 0, stream>>>(
            packed, cand32, wpk, nrm32, cb, wsB, wsZ);
        k_refine<<<NROWS / 4, 256, 0, stream>>>(xT, invn64, sqd, cand32, e0);
        k_out2  <<<B_ * 588, 256, 0, stream>>>(e0, gam, bet, out0,
                                               wsB, wsZ, e1);
    } else if (ws_size >= ZF_BYTES) {
        // MEDIUM: all-batch fp32 B in d_ws, fused epilogue.
        k_screen_mfma<<<NSCRB, 256, 0, stream>>>(packed, cand32);
        k_refine<<<NROWS / 4, 256, 0, stream>>>(xT, invn64, sqd, cand32, e0);
        k_gemmB<<<B_ * 49 * 6, 256, 0, stream>>>(
            x, cw, d_ws, 0, 0, 384, 0, 6, BSTRIDE);
        k_outA <<<B_ * 49 * 6, 256, 0, stream>>>(
            x, cw, e0, cb, gam, bet, out0, (const void*)d_ws,
            0, 0, 0, 384, 0, 6, BSTRIDE);
        k_center<<<(NROWS * KNN + 255) / 256, 256, 0, stream>>>(e1);
    } else {
        // FALLBACK: d_out aliasing discipline (R3-proven numerics).
        k_screen_mfma<<<NSCRB, 256, 0, stream>>>(packed, cand32);
        k_refine<<<NROWS / 4, 256, 0, stream>>>(xT, invn64, sqd, cand32, e0);
        k_gemmB<<<2 * 49 * 6, 256, 0, stream>>>(
            x, cw, (void*)ou, 2, 0, 384, 0, 6, BSTRIDE);
        k_outA <<<2 * 49 * 6, 256, 0, stream>>>(
            x, cw, e0, cb, gam, bet, out0, (const void*)ou,
            2, 0, 0, 384, 0, 6, BSTRIDE);
        k_gemmB<<<49 * 6, 256, 0, stream>>>(
            x, cw, (void*)ou, 1, 0, 384, 0, 6, 0);
        k_outA <<<49 * 6, 256, 0, stream>>>(
            x, cw, e0, cb, gam, bet, out0, (const void*)ou,
            1, 0, 0, 384, 0, 6, 0);
        k_gemmB<<<49 * 3, 256, 0, stream>>>(
            x, cw, (void*)ou, 0, 192, 192, 1, 3, 0);
        k_outA <<<49 * 3, 256, 0, stream>>>(
            x, cw, e0, cb, gam, bet, out0, (const void*)ou,
            0, 192, 192, 192, 1, 3, 0);
        k_gemmB<<<49 * 2, 256, 0, stream>>>(
            x, cw, (void*)ou, 0, 64, 128, 1, 2, 0);
        k_outA <<<49 * 2, 256, 0, stream>>>(
            x, cw, e0, cb, gam, bet, out0, (const void*)ou,
            0, 64, 64, 128, 1, 2, 0);
        k_gemmB<<<49 * 1, 256, 0, stream>>>(
            x, cw, (void*)e1, 0, 0, 64, 1, 1, 0);
        k_outA <<<49 * 1, 256, 0, stream>>>(
            x, cw, e0, cb, gam, bet, out0, (const void*)e1,
            0, 0, 0, 64, 1, 1, 0);
        k_center<<<(NROWS * KNN + 255) / 256, 256, 0, stream>>>(e1);
    }
}